// Round 1
// baseline (44.237 us; speedup 1.0000x reference)
//
#include <hip/hip_runtime.h>
#include <hip/hip_bf16.h>

// DeepPoly ReLU transformer + back-substitution, fused to 2 dots per row.
// out[0:N]   = max(lb0, beta*(A+bias))
// out[N:2N]  = min(ub0, lmbda*(B+bias)+mu)
// A = sum_j w>0 ? w*lo : w*up ;  B = sum_j w>0 ? w*up : w*lo

__global__ __launch_bounds__(256) void deeppoly_relu_kernel(
    const float* __restrict__ bounds,   // [2, N]
    const float* __restrict__ weight,   // [N, M]
    const float* __restrict__ bias,     // [N]
    const float* __restrict__ in_lower, // [M]
    const float* __restrict__ in_upper, // [M]
    float* __restrict__ out,            // [2, N]
    int N, int M)
{
    const int row = blockIdx.x;
    if (row >= N) return;

    const float4* __restrict__ wrow =
        reinterpret_cast<const float4*>(weight + (size_t)row * (size_t)M);
    const float4* __restrict__ lo4 = reinterpret_cast<const float4*>(in_lower);
    const float4* __restrict__ up4 = reinterpret_cast<const float4*>(in_upper);

    const int nvec = M >> 2;  // M/4 float4s
    float A = 0.f, B = 0.f;

    for (int i = threadIdx.x; i < nvec; i += blockDim.x) {
        float4 w  = wrow[i];
        float4 lo = lo4[i];
        float4 up = up4[i];

        A = fmaf(w.x, (w.x > 0.f ? lo.x : up.x), A);
        B = fmaf(w.x, (w.x > 0.f ? up.x : lo.x), B);
        A = fmaf(w.y, (w.y > 0.f ? lo.y : up.y), A);
        B = fmaf(w.y, (w.y > 0.f ? up.y : lo.y), B);
        A = fmaf(w.z, (w.z > 0.f ? lo.z : up.z), A);
        B = fmaf(w.z, (w.z > 0.f ? up.z : lo.z), B);
        A = fmaf(w.w, (w.w > 0.f ? lo.w : up.w), A);
        B = fmaf(w.w, (w.w > 0.f ? up.w : lo.w), B);
    }

    // wave (64-lane) butterfly reduce
    #pragma unroll
    for (int off = 32; off > 0; off >>= 1) {
        A += __shfl_down(A, off, 64);
        B += __shfl_down(B, off, 64);
    }

    __shared__ float sA[4], sB[4];
    const int lane = threadIdx.x & 63;
    const int wid  = threadIdx.x >> 6;
    if (lane == 0) { sA[wid] = A; sB[wid] = B; }
    __syncthreads();

    if (threadIdx.x == 0) {
        A = sA[0] + sA[1] + sA[2] + sA[3];
        B = sB[0] + sB[1] + sB[2] + sB[3];

        const float l = bounds[row];
        const float u = bounds[N + row];
        const bool ind2 = (l >= 0.f);
        const bool ind3 = (u > 0.f) && (l < 0.f);

        const float diff  = ind3 ? (u - l) : 1.f;
        const float lmbda = ind2 ? 1.f : (ind3 ? (u / diff) : 0.f);
        const float beta  = ind2 ? 1.f : 0.f;
        const float mu    = ind3 ? (-l * u / diff) : 0.f;
        const float lb0   = ind2 ? l : 0.f;
        const float ub0   = ind2 ? u : (ind3 ? u : 0.f);

        const float b = bias[row];
        const float new_l = beta * (A + b);
        const float new_u = fmaf(lmbda, B + b, mu);

        out[row]     = fmaxf(lb0, new_l);
        out[N + row] = fminf(ub0, new_u);
    }
}

extern "C" void kernel_launch(void* const* d_in, const int* in_sizes, int n_in,
                              void* d_out, int out_size, void* d_ws, size_t ws_size,
                              hipStream_t stream) {
    const float* bounds   = (const float*)d_in[0];  // [2, N]
    const float* weight   = (const float*)d_in[1];  // [N, M]
    const float* bias     = (const float*)d_in[2];  // [N]
    const float* in_lower = (const float*)d_in[3];  // [M]
    const float* in_upper = (const float*)d_in[4];  // [M]
    float* out = (float*)d_out;                     // [2, N]

    const int N = in_sizes[2];            // 8192
    const int M = in_sizes[3];            // 8192

    deeppoly_relu_kernel<<<N, 256, 0, stream>>>(
        bounds, weight, bias, in_lower, in_upper, out, N, M);
}